// Round 9
// baseline (148.494 us; speedup 1.0000x reference)
//
#include <hip/hip_runtime.h>

// Shapes (fixed by the problem):
#define F   256   // NUM_FEATURES
#define T   64    // SEQ (token axis)
#define NH  8     // heads
#define D   32    // head dim
#define NA  8     // agents
#define NBB 32    // batch per agent

typedef unsigned short ushortT;
typedef unsigned int   uintT;

typedef short bf16x8 __attribute__((ext_vector_type(8)));
typedef float f32x4  __attribute__((ext_vector_type(4)));

__device__ __forceinline__ float bf2f(ushortT u) {
    union { uintT i; float f; } c; c.i = ((uintT)u) << 16; return c.f;
}
__device__ __forceinline__ ushortT f2bf(float f) {
    union { float f; uintT u; } c; c.f = f;
    uintT u = c.u;
    uintT r = u + 0x7fffu + ((u >> 16) & 1u);   // RNE
    return (ushortT)(r >> 16);
}

// Packed f32->bf16 conversion (1 VALU op for 2 values, RNE; T12 recipe).
__device__ __forceinline__ uintT cvt_pk_bf16(float lo, float hi) {
    uintT r;
    asm("v_cvt_pk_bf16_f32 %0, %1, %2" : "=v"(r) : "v"(lo), "v"(hi));
    return r;
}
__device__ __forceinline__ void packc1(const f32x4 v, uintT& u0, uintT& u1) {
    u0 = cvt_pk_bf16(v[0], v[1]);
    u1 = cvt_pk_bf16(v[2], v[3]);
}
__device__ __forceinline__ void packcs(const f32x4 v, float s, uintT& u0, uintT& u1) {
    u0 = cvt_pk_bf16(v[0] * s, v[1] * s);
    u1 = cvt_pk_bf16(v[2] * s, v[3] * s);
}

__device__ __forceinline__ float fexp2(float x) {
#if __has_builtin(__builtin_amdgcn_exp2f)
    return __builtin_amdgcn_exp2f(x);
#else
    float r; asm("v_exp_f32 %0, %1" : "=v"(r) : "v"(x)); return r;
#endif
}
__device__ __forceinline__ float frcp(float x) {
#if __has_builtin(__builtin_amdgcn_rcpf)
    return __builtin_amdgcn_rcpf(x);
#else
    float r; asm("v_rcp_f32 %0, %1" : "=v"(r) : "v"(x)); return r;
#endif
}

// Runtime dtype detection (verified: harness inputs are fp32).
__device__ __forceinline__ int detect_isbf16(const void* xraw) {
    const uintT* w = (const uintT*)xraw;
    int bad = 0;
    for (int k = 0; k < 128; ++k) {
        uintT v = w[k];
        uintT e0 = (v >> 7)  & 0xffu;
        uintT e1 = (v >> 23) & 0xffu;
        bad += (e0 > 131u) + (e1 > 131u);
    }
    return bad == 0 ? 1 : 0;
}

__device__ __forceinline__ ushortT cvt_elem(const void* p, size_t i, bool isbf) {
    return isbf ? ((const ushortT*)p)[i] : f2bf(((const float*)p)[i]);
}

// C-layout -> A/B-fragment transform via register shuffles (verified).
__device__ __forceinline__ bf16x8 build_frag(uintT u0a, uintT u1a, uintT u0b, uintT u1b,
                                             int sl0, int sl1, bool hi) {
    union { uintT u[4]; bf16x8 v; } r;
    uintT x0a = (uintT)__shfl((int)u0a, sl0), x0b = (uintT)__shfl((int)u0b, sl0);
    uintT x1a = (uintT)__shfl((int)u1a, sl0), x1b = (uintT)__shfl((int)u1b, sl0);
    uintT x2a = (uintT)__shfl((int)u0a, sl1), x2b = (uintT)__shfl((int)u0b, sl1);
    uintT x3a = (uintT)__shfl((int)u1a, sl1), x3b = (uintT)__shfl((int)u1b, sl1);
    r.u[0] = hi ? x0b : x0a;
    r.u[1] = hi ? x1b : x1a;
    r.u[2] = hi ? x2b : x2a;
    r.u[3] = hi ? x3b : x3a;
    return r.v;
}

// LDS tile: row t, 16B chunks XOR-swizzled by t -> b128 frag reads spread over
// all 8 bank-groups (2-way max = free per m136).  t is the LOCAL row (0..31).
__device__ __forceinline__ int xposU(int t, int f) {
    return t * 256 + ((((f >> 3) ^ (t & 31)) * 8) | (f & 7));
}
#define FRAGPOS(t_, ks_, quad_) \
    ((t_) * 256 + ((((4 * (ks_) + (quad_)) ^ ((t_) & 31)) * 8)))

// ===========================================================================
// ws layout (bytes) — needA = 17301504:
//   0        Wt   [c'=1024][f=256] bf16   524288
//            (c'<256:Q, <512:K, <768:V, >=768: Wp[g][c])
//   524288   Kws  [nb][h][s][d] bf16     8388608
//   8912896  Vws  [nb][h][d][s] bf16     8388608  (transposed)
// ===========================================================================

// K0: weight prep. 262144 elems, grid 128 x 256, 8 elems/thread.
__global__ __launch_bounds__(256) void wprep_kernel(const void* __restrict__ Wq,
                                                    const void* __restrict__ Wk,
                                                    const void* __restrict__ Wv,
                                                    const void* __restrict__ Wp,
                                                    const void* __restrict__ x,
                                                    ushortT* __restrict__ Wt) {
    __shared__ int sflag;
    if (threadIdx.x == 0) sflag = detect_isbf16(x);
    __syncthreads();
    bool isbf = sflag != 0;

    int base = (blockIdx.x * 256 + threadIdx.x) * 8;   // < 262144
    int cp = base >> 8, f0 = base & 255;

    ushortT tmp[8];
    if (cp < 768) {   // QKV: transpose W*[h][f][d] -> Wt[c'][f]
        int qkv = cp >> 8, c = cp & 255, hh = c >> 5, d = c & 31;
        const void* W = (qkv == 0) ? Wq : (qkv == 1) ? Wk : Wv;
        #pragma unroll
        for (int jj = 0; jj < 8; ++jj)
            tmp[jj] = cvt_elem(W, (size_t)(hh * F + f0 + jj) * D + d, isbf);
    } else {          // Wp[g][c] straight copy (already row-major in c)
        int g = cp - 768;
        #pragma unroll
        for (int jj = 0; jj < 8; ++jj)
            tmp[jj] = cvt_elem(Wp, (size_t)g * F + f0 + jj, isbf);
    }
    *(uint4*)&Wt[base] = *(const uint4*)tmp;
}

// Stage full x[nb] tile -> xs[t64][f^swz] (32 KB).
template <int NT>
__device__ __forceinline__ void stage_xT(const void* x, int nb, ushortT* xs,
                                         bool isbf, int tid) {
    int t = tid & 63;
    int g0 = tid >> 6;
    const int GP = NT / 64;
    #pragma unroll
    for (int it = 0; it < 64 / GP; ++it) {
        int g = g0 + it * GP;
        float v0, v1, v2, v3;
        if (isbf) {
            const ushortT* xp = (const ushortT*)x + (size_t)nb * (F * T) + (size_t)g * 4 * T + t;
            v0 = bf2f(xp[0]); v1 = bf2f(xp[T]); v2 = bf2f(xp[2 * T]); v3 = bf2f(xp[3 * T]);
        } else {
            const float* xp = (const float*)x + (size_t)nb * (F * T) + (size_t)g * 4 * T + t;
            v0 = xp[0]; v1 = xp[T]; v2 = xp[2 * T]; v3 = xp[3 * T];
        }
        uintT lo  = cvt_pk_bf16(v0, v1);
        uintT hi2 = cvt_pk_bf16(v2, v3);
        *(uint2*)&xs[xposU(t & 31, g * 4) + (t >> 5) * 8192] = make_uint2(lo, hi2);
    }
}

// ---------------------------------------------------------------------------
// K1: K/V projection GEMM.  grid = 256 (1-D), 512 thr (8 waves).
// Waves 0-3 compute K rows (Wt 256..511), waves 4-7 V rows (512..767),
// sharing ONE x-stage (R14 merge, verified -6 µs).
// R15: XCD-aware block swizzle (T1) — decode nb so batch-column b is a
// function of (launch_id & 7) = XCD: the K/V this block WRITES will be READ
// by attn blocks placed on the SAME XCD -> stays in that XCD's L2.
// ---------------------------------------------------------------------------
__global__ __launch_bounds__(512) void qkv_kernel(const void* __restrict__ x,
                                                  const ushortT* __restrict__ Wt,
                                                  ushortT* __restrict__ Kws,
                                                  ushortT* __restrict__ Vws) {
    int f_ = blockIdx.x;                       // 0..255
    int r_  = f_ & 7;                          // XCD slot
    int ia  = (f_ >> 3) & 7;                   // agent
    int c_  = (f_ >> 6) & 3;                   // b within XCD group
    int nb  = ia * 32 + (4 * r_ + c_);         // bijective over [0,256)

    __shared__ __align__(16) ushortT xs[T * F];   // 32 KB
    __shared__ int sflag;
    int tid = threadIdx.x;
    if (tid == 0) sflag = detect_isbf16(x);
    __syncthreads();
    bool isbf = sflag != 0;
    stage_xT<512>(x, nb, xs, isbf, tid);
    __syncthreads();

    int w = tid >> 6, lane = tid & 63, l15 = lane & 15, quad = lane >> 4;
    int half = w >> 2;                 // 0 = K (waves 0-3), 1 = V (waves 4-7)
    int rowbase = 256 + 64 * w;        // spans K rows then V rows

    f32x4 acc[4][4];
    #pragma unroll
    for (int a = 0; a < 4; ++a)
        #pragma unroll
        for (int c = 0; c < 4; ++c) acc[a][c] = (f32x4){0.f, 0.f, 0.f, 0.f};

    #pragma unroll
    for (int ks = 0; ks < 8; ++ks) {
        bf16x8 Bfr[4];
        #pragma unroll
        for (int nt = 0; nt < 4; ++nt) {
            int t = 16 * nt + l15;
            Bfr[nt] = *(const bf16x8*)&xs[FRAGPOS(t & 31, ks, quad) + (t >> 5) * 8192];
        }
        #pragma unroll
        for (int mt = 0; mt < 4; ++mt) {
            bf16x8 Afr = *(const bf16x8*)(Wt +
                (size_t)(rowbase + 16 * mt + l15) * 256 + ks * 32 + quad * 8);
            #pragma unroll
            for (int nt = 0; nt < 4; ++nt)
                acc[mt][nt] = __builtin_amdgcn_mfma_f32_16x16x32_bf16(Afr, Bfr[nt],
                                                                      acc[mt][nt], 0, 0, 0);
        }
    }

    #pragma unroll
    for (int mt = 0; mt < 4; ++mt) {
        int rel = 64 * (w & 3) + 16 * mt + 4 * quad;   // 0..255 within K or V block
        int hh = rel >> 5, db = rel & 31;
        #pragma unroll
        for (int nt = 0; nt < 4; ++nt) {
            int t = 16 * nt + l15;
            f32x4 v = acc[mt][nt];
            if (half == 0) {   // K: [nb][h][s=t][d]
                ushortT* dst = Kws + ((size_t)(nb * NH + hh) * T + t) * D + db;
                uintT lo  = cvt_pk_bf16(v[0], v[1]);
                uintT hi2 = cvt_pk_bf16(v[2], v[3]);
                *(uint2*)dst = make_uint2(lo, hi2);
            } else {           // V transposed: [nb][h][d][s=t]
                uintT p0 = cvt_pk_bf16(v[0], v[1]);
                uintT p1 = cvt_pk_bf16(v[2], v[3]);
                size_t vb = (size_t)(nb * NH + hh) * D + db;
                Vws[(vb + 0) * T + t] = (ushortT)p0;
                Vws[(vb + 1) * T + t] = (ushortT)(p0 >> 16);
                Vws[(vb + 2) * T + t] = (ushortT)p1;
                Vws[(vb + 3) * T + t] = (ushortT)(p1 >> 16);
            }
        }
    }
}

// ---------------------------------------------------------------------------
// K2: Q-GEMM + attention + projection over a 32-token half.
// grid = 512 (1-D), 512 thr, wave = head h.  Body = R0/R14-verified (52.5 µs).
// R15: XCD-aware swizzle (T1) — the 16 blocks sharing batch-column b (8 j x
// 2 tb) all read the SAME 512 KB K/V slice.  Default dispatch round-robins
// them across 8 XCDs -> the slice is re-fetched into every XCD L2 (16.8 MB
// total K/V vs 4 MB L2) -> loads are L3-latency (~600+ cyc), unhideable at
// 3 waves/SIMD (measured: MfmaUtil 8.5%, VALUBusy 20%, occupancy 34%).
// Decode b from (launch_id & 7) = XCD: 4 b-columns/XCD = 2 MB K/V,
// L2-resident, produced on the same XCD by qkv's matching swizzle.
// ---------------------------------------------------------------------------
__global__ __launch_bounds__(512, 2) void attn_kernel(const void* __restrict__ x,
                                                      const ushortT* __restrict__ Wt,
                                                      const ushortT* __restrict__ Kws,
                                                      const ushortT* __restrict__ Vws,
                                                      const void* __restrict__ bp,
                                                      void* __restrict__ outp) {
    __shared__ __align__(16) ushortT xs[32 * F];   // 16 KB
    __shared__ float bpf[F];
    __shared__ int sflag;

    int tid = threadIdx.x;
    int f_ = blockIdx.x;                 // 0..511
    int b  = 4 * (f_ & 7) + ((f_ >> 3) & 3);
    int j  = (f_ >> 5) & 7;
    int tb = (f_ >> 8) & 1;
    int nbj = j * NBB + b;

    if (tid == 0) sflag = detect_isbf16(x);
    __syncthreads();
    bool isbf = sflag != 0;

    // stage x half-tile: lane = local t (0..31), 16 f-groups x 4 iters
    {
        int t = tid & 31, fg = tid >> 5;
        int ta = tb * 32 + t;
        #pragma unroll
        for (int it = 0; it < 4; ++it) {
            int f0 = (fg + 16 * it) * 4;
            float v0, v1, v2, v3;
            if (isbf) {
                const ushortT* xp = (const ushortT*)x + (size_t)nbj * (F * T) +
                                    (size_t)f0 * T + ta;
                v0 = bf2f(xp[0]); v1 = bf2f(xp[T]); v2 = bf2f(xp[2 * T]); v3 = bf2f(xp[3 * T]);
            } else {
                const float* xp = (const float*)x + (size_t)nbj * (F * T) +
                                  (size_t)f0 * T + ta;
                v0 = xp[0]; v1 = xp[T]; v2 = xp[2 * T]; v3 = xp[3 * T];
            }
            uintT lo  = cvt_pk_bf16(v0, v1);
            uintT hi2 = cvt_pk_bf16(v2, v3);
            *(uint2*)&xs[xposU(t, f0)] = make_uint2(lo, hi2);
        }
    }
    if (tid < 256)
        bpf[tid] = isbf ? bf2f(((const ushortT*)bp)[tid]) : ((const float*)bp)[tid];
    __syncthreads();

    int h = tid >> 6, lane = tid & 63, l15 = lane & 15, quad = lane >> 4;
    bool hi = quad >= 2;
    int sl0 = l15 + 32 * (quad & 1), sl1 = sl0 + 16;

    // ---- Q-GEMM: rows 32h..32h+31, cols = 32 local t
    // scale = 1/16 * log2e (scores in log2-domain; softmax uses exp2).
    const float QS = 0.0625f * 1.44269504089f;
    bf16x8 qf[2];
    {
        f32x4 qacc[2][2];
        #pragma unroll
        for (int mt = 0; mt < 2; ++mt)
            #pragma unroll
            for (int nt = 0; nt < 2; ++nt) qacc[mt][nt] = (f32x4){0.f, 0.f, 0.f, 0.f};
        #pragma unroll
        for (int ks = 0; ks < 8; ++ks) {
            bf16x8 xf[2];
            #pragma unroll
            for (int nt = 0; nt < 2; ++nt)
                xf[nt] = *(const bf16x8*)&xs[FRAGPOS(16 * nt + l15, ks, quad)];
            #pragma unroll
            for (int mt = 0; mt < 2; ++mt) {
                bf16x8 Aw = *(const bf16x8*)(Wt +
                    (size_t)(32 * h + 16 * mt + l15) * 256 + ks * 32 + quad * 8);
                #pragma unroll
                for (int nt = 0; nt < 2; ++nt)
                    qacc[mt][nt] = __builtin_amdgcn_mfma_f32_16x16x32_bf16(
                        Aw, xf[nt], qacc[mt][nt], 0, 0, 0);
            }
        }
        #pragma unroll
        for (int tt = 0; tt < 2; ++tt) {
            uintT a0, a1, b0, b1;
            packcs(qacc[0][tt], QS, a0, a1);
            packcs(qacc[1][tt], QS, b0, b1);
            qf[tt] = build_frag(a0, a1, b0, b1, sl0, sl1, hi);
        }
    }

    f32x4 oacc[2][2];
    #pragma unroll
    for (int mt = 0; mt < 2; ++mt)
        #pragma unroll
        for (int tt = 0; tt < 2; ++tt) oacc[mt][tt] = (f32x4){0.f, 0.f, 0.f, 0.f};

    // ---- key-agent loop (no barriers; modest register footprint)
    for (int i = 0; i < NA; ++i) {
        int nbi = i * NBB + b;
        const ushortT* Kb = Kws + (size_t)(nbi * NH + h) * T * D;
        const ushortT* Vb = Vws + (size_t)(nbi * NH + h) * D * T;

        float psum[2] = {0.f, 0.f};
        f32x4 pv[2][2];
        #pragma unroll
        for (int mt = 0; mt < 2; ++mt)
            #pragma unroll
            for (int tt = 0; tt < 2; ++tt) pv[mt][tt] = (f32x4){0.f, 0.f, 0.f, 0.f};

        #pragma unroll
        for (int kx = 0; kx < 2; ++kx) {
            // hoist all 4 frag loads for this k-chunk ahead of the
            // exp/pack/shuffle dependency chain
            bf16x8 kfr[2];
            kfr[0] = *(const bf16x8*)(Kb + (16 * (2 * kx + 0) + l15) * D + quad * 8);
            kfr[1] = *(const bf16x8*)(Kb + (16 * (2 * kx + 1) + l15) * D + quad * 8);
            bf16x8 vf0 = *(const bf16x8*)(Vb + l15 * T + kx * 32 + quad * 8);
            bf16x8 vf1 = *(const bf16x8*)(Vb + (16 + l15) * T + kx * 32 + quad * 8);

            // S for st-pair {2kx, 2kx+1}: exp2 (unnormalized) -> packed P
            uintT pu0[2][2], pu1[2][2];   // [sp][tt]
            #pragma unroll
            for (int sp = 0; sp < 2; ++sp) {
                #pragma unroll
                for (int tt = 0; tt < 2; ++tt) {
                    f32x4 s4 = __builtin_amdgcn_mfma_f32_16x16x32_bf16(
                        kfr[sp], qf[tt], (f32x4){0.f, 0.f, 0.f, 0.f}, 0, 0, 0);
                    float e0 = fexp2(s4[0]);
                    float e1 = fexp2(s4[1]);
                    float e2 = fexp2(s4[2]);
                    float e3 = fexp2(s4[3]);
                    psum[tt] += (e0 + e1) + (e2 + e3);
                    pu0[sp][tt] = cvt_pk_bf16(e0, e1);
                    pu1[sp][tt] = cvt_pk_bf16(e2, e3);
                }
            }
            // PV for this k-chunk
            #pragma unroll
            for (int tt = 0; tt < 2; ++tt) {
                bf16x8 pf = build_frag(pu0[0][tt], pu1[0][tt], pu0[1][tt], pu1[1][tt],
                                       sl0, sl1, hi);
                pv[0][tt] = __builtin_amdgcn_mfma_f32_16x16x32_bf16(
                    vf0, pf, pv[0][tt], 0, 0, 0);
                pv[1][tt] = __builtin_amdgcn_mfma_f32_16x16x32_bf16(
                    vf1, pf, pv[1][tt], 0, 0, 0);
            }
        }

        #pragma unroll
        for (int tt = 0; tt < 2; ++tt) {
            float s = psum[tt];
            s += __shfl_xor(s, 16);
            s += __shfl_xor(s, 32);
            float inv = frcp(s);
            #pragma unroll
            for (int mt = 0; mt < 2; ++mt)
                #pragma unroll
                for (int r = 0; r < 4; ++r)
                    oacc[mt][tt][r] = fmaf(inv, pv[mt][tt][r], oacc[mt][tt][r]);
        }
    }

    // ---- epilogue: Y[t32][c] -> xs (swizzled), then projection
    __syncthreads();
    #pragma unroll
    for (int mt = 0; mt < 2; ++mt)
        #pragma unroll
        for (int tt = 0; tt < 2; ++tt) {
            int t = 16 * tt + l15;
            int cb = 32 * h + 16 * mt + 4 * quad;
            uintT u0, u1;
            packc1(oacc[mt][tt], u0, u1);
            *(uint2*)&xs[xposU(t, cb)] = make_uint2(u0, u1);
        }
    __syncthreads();

    // OUT[g][t32] = Wp[g][c] . Y[t][c] + bp[g];  wave h -> g-tiles 2h, 2h+1
    f32x4 cacc[2][2];
    #pragma unroll
    for (int a = 0; a < 2; ++a)
        #pragma unroll
        for (int c = 0; c < 2; ++c) cacc[a][c] = (f32x4){0.f, 0.f, 0.f, 0.f};

    #pragma unroll
    for (int ks = 0; ks < 8; ++ks) {
        bf16x8 yb[2];
        #pragma unroll
        for (int nt = 0; nt < 2; ++nt)
            yb[nt] = *(const bf16x8*)&xs[FRAGPOS(16 * nt + l15, ks, quad)];
        #pragma unroll
        for (int m2 = 0; m2 < 2; ++m2) {
            int g = 16 * (2 * h + m2) + l15;
            bf16x8 wf = *(const bf16x8*)(Wt + (size_t)(768 + g) * 256 + ks * 32 + quad * 8);
            #pragma unroll
            for (int nt = 0; nt < 2; ++nt)
                cacc[m2][nt] = __builtin_amdgcn_mfma_f32_16x16x32_bf16(
                    wf, yb[nt], cacc[m2][nt], 0, 0, 0);
        }
    }

    #pragma unroll
    for (int m2 = 0; m2 < 2; ++m2)
        #pragma unroll
        for (int nt = 0; nt < 2; ++nt) {
            int t = tb * 32 + 16 * nt + l15;
            #pragma unroll
            for (int r = 0; r < 4; ++r) {
                int g = 16 * (2 * h + m2) + 4 * quad + r;
                float val = cacc[m2][nt][r] + bpf[g];
                if (isbf)
                    ((ushortT*)outp)[(size_t)nbj * F * T + g * T + t] = f2bf(val);
                else
                    ((float*)outp)[(size_t)nbj * F * T + g * T + t] = val;
            }
        }
}

// ===========================================================================
// PATH B: zero-workspace scalar fallback (verified, dtype-flexible).
// ===========================================================================
__device__ __forceinline__ float tof(ushortT u) { return bf2f(u); }
__device__ __forceinline__ float tof(float f)   { return f; }

__device__ __forceinline__ void stage_x(const void* x, size_t nb, ushortT* sX,
                                        bool isbf, int tid) {
    if (isbf) {
        const int4* xg = (const int4*)((const ushortT*)x + nb * (F * T));
        int4* xl = (int4*)sX;
        for (int kk = tid; kk < F * T / 8; kk += 512) xl[kk] = xg[kk];
    } else {
        const float4* xg = (const float4*)((const float*)x + nb * (F * T));
        for (int kk = tid; kk < F * T / 4; kk += 512) {
            float4 v = xg[kk];
            int o = kk * 4;
            sX[o + 0] = f2bf(v.x); sX[o + 1] = f2bf(v.y);
            sX[o + 2] = f2bf(v.z); sX[o + 3] = f2bf(v.w);
        }
    }
}

template <typename WT>
__device__ __forceinline__ void q_proj(const WT* __restrict__ W, const ushortT* sX,
                                       ushortT* dst, int c, int t0) {
    float acc[32];
    #pragma unroll
    for (int m = 0; m < 32; ++m) acc[m] = 0.f;
    for (int f = 0; f < F; ++f) {
        float w = tof(W[f * D]);
        const ushortT* xr = &sX[f * T + t0];
        #pragma unroll
        for (int m = 0; m < 32; ++m) acc[m] = fmaf(bf2f(xr[m]), w, acc[m]);
    }
    #pragma unroll
    for (int m = 0; m < 32; ++m) dst[(t0 + m) * F + c] = f2bf(acc[m]);
}

template <typename WT>
__device__ __forceinline__ void kv_proj(const WT* __restrict__ WK, const WT* __restrict__ WV,
                                        const ushortT* sX, ushortT* sK, ushortT* sV,
                                        int c, int t0) {
    float ak[32], av[32];
    #pragma unroll
    for (int m = 0; m < 32; ++m) { ak[m] = 0.f; av[m] = 0.f; }
    for (int f = 0; f < F; ++f) {
        float wk = tof(WK[f * D]);
        float wv = tof(WV[f * D]);
        const ushortT* xr = &sX[f * T + t0];
        #pragma unroll
        for (int m = 0; m < 32; ++m) {
            float xv = bf2f(xr[m]);
            ak[m] = fmaf(xv, wk, ak[m]);
            av[m] = fmaf(xv, wv, av[m]);
        }
    }
    #pragma unroll
    for (int m = 0; m < 32; ++m) {
        sK[(t0 + m) * F + c] = f2bf(ak[m]);
        sV[(t0 + m) * F + c] = f2bf(av[m]);
    }
}

__global__ __launch_bounds__(512) void fused_kernel(const void* __restrict__ x,
                                                    const void* __restrict__ Wq,
                                                    const void* __restrict__ Wk,
                                                    const void* __restrict__ Wv,
                                                    const void* __restrict__ Wp,
                                                    const void* __restrict__ bp,
                                                    void* __restrict__ outp) {
    __shared__ __align__(16) char smem[98304];
    __shared__ int sflag;
    ushortT* sX = (ushortT*)smem;
    ushortT* sK = (ushortT*)(smem + 32768);
    ushortT* sV = (ushortT*)(smem + 65536);
    float*   sO = (float*)smem;

    int tid = threadIdx.x;
    int b = blockIdx.x, j = blockIdx.y;
    size_t nbj = (size_t)j * NBB + b;

    if (tid == 0) sflag = detect_isbf16(x);
    __syncthreads();
    bool isbf = sflag != 0;

    stage_x(x, nbj, sX, isbf, tid);
    __syncthreads();

    int c = tid & 255, t0 = (tid >> 8) * 32;
    int hc = c >> 5, dc = c & 31;
    if (isbf) q_proj((const ushortT*)Wq + (size_t)hc * F * D + dc, sX, sK, c, t0);
    else      q_proj((const float*)Wq   + (size_t)hc * F * D + dc, sX, sK, c, t0);
    __syncthreads();

    int h = tid >> 6, t = tid & 63;
    float q[32], o[32];
    #pragma unroll
    for (int dd = 0; dd < 32; ++dd) { q[dd] = bf2f(sK[t * F + h * D + dd]); o[dd] = 0.f; }

    for (int i = 0; i < NA; ++i) {
        __syncthreads();
        stage_x(x, (size_t)(i * NBB + b), sX, isbf, tid);
        __syncthreads();
        if (isbf) kv_proj((const ushortT*)Wk + (size_t)hc * F * D + dc,
                          (const ushortT*)Wv + (size_t)hc * F * D + dc, sX, sK, sV, c, t0);
        else      kv_proj((const float*)Wk   + (size_t)hc * F * D + dc,
                          (const float*)Wv   + (size_t)hc * F * D + dc, sX, sK, sV, c, t0);
        __syncthreads();
        float l = 0.f;
        float oi[32];
        #pragma unroll
        for (int dd = 0; dd < 32; ++dd) oi[dd] = 0.f;
        for (int s = 0; s < T; ++s) {
            const ushortT* kr = &sK[s * F + h * D];
            float dot = 0.f;
            #pragma unroll
            for (int dd = 0; dd < 32; ++dd) dot = fmaf(q[dd], bf2f(kr[dd]), dot);
            float e = __expf(dot * 0.0625f);
            l += e;
            const ushortT* vr = &sV[s * F + h * D];
            #pragma unroll
            for (int dd = 0; dd < 32; ++dd) oi[dd] = fmaf(e, bf2f(vr[dd]), oi[dd]);
        }
        float inv = 1.0f / l;
        #pragma unroll
        for (int dd = 0; dd < 32; ++dd) o[dd] = fmaf(inv, oi[dd], o[dd]);
    }
    __syncthreads();

    #pragma unroll
    for (int dd = 0; dd < 32; ++dd) sO[(h * D + dd) * T + t] = o[dd];
    __syncthreads();

    {
        int g = tid >> 1, te0 = (tid & 1) * 32;
        float acc[32];
        #pragma unroll
        for (int m = 0; m < 32; ++m) acc[m] = 0.f;
        if (isbf) {
            const ushortT* Wrow = (const ushortT*)Wp + (size_t)g * F;
            for (int cc = 0; cc < F; ++cc) {
                float w = bf2f(Wrow[cc]);
                const float* yr = &sO[cc * T + te0];
                #pragma unroll
                for (int m = 0; m < 32; ++m) acc[m] = fmaf(yr[m], w, acc[m]);
            }
        } else {
            const float* Wrow = (const float*)Wp + (size_t)g * F;
            for (int cc = 0; cc < F; ++cc) {
                float w = Wrow[cc];
                const float* yr = &sO[cc * T + te0];
                #pragma unroll
                for (int m = 0; m < 32; ++m) acc[m] = fmaf(yr[m], w, acc[m]);
            }
        }
        float bias = isbf ? bf2f(((const ushortT*)bp)[g]) : ((const float*)bp)[g];
        if (isbf) {
            ushortT* ob = (ushortT*)outp + nbj * F * T + g * T + te0;
            #pragma unroll
            for (int m = 0; m < 32; ++m) ob[m] = f2bf(acc[m] + bias);
        } else {
            float* ob = (float*)outp + nbj * F * T + g * T + te0;
            #pragma unroll
            for (int m = 0; m < 32; ++m) ob[m] = acc[m] + bias;
        }
    }
}

// ---------------------------------------------------------------------------
extern "C" void kernel_launch(void* const* d_in, const int* in_sizes, int n_in,
                              void* d_out, int out_size, void* d_ws, size_t ws_size,
                              hipStream_t stream) {
    const void* x  = d_in[0];
    const void* Wq = d_in[1];
    const void* Wk = d_in[2];
    const void* Wv = d_in[3];
    const void* Wp = d_in[4];
    const void* bp = d_in[5];

    const size_t needA = 17301504;   // Wt(1024 rows) + Kws + Vws

    if (ws_size >= needA) {
        char* ws = (char*)d_ws;
        ushortT* Wt  = (ushortT*)(ws + 0);
        ushortT* Kws = (ushortT*)(ws + 524288);
        ushortT* Vws = (ushortT*)(ws + 8912896);

        wprep_kernel<<<dim3(128), dim3(256), 0, stream>>>(Wq, Wk, Wv, Wp, x, Wt);
        qkv_kernel  <<<dim3(256), dim3(512), 0, stream>>>(x, Wt, Kws, Vws);
        attn_kernel <<<dim3(512), dim3(512), 0, stream>>>(x, Wt, Kws, Vws, bp, d_out);
    } else {
        fused_kernel<<<dim3(32, 8), dim3(512), 0, stream>>>(x, Wq, Wk, Wv, Wp, bp, d_out);
    }
}

// Round 10
// 146.049 us; speedup vs baseline: 1.0167x; 1.0167x over previous
//
#include <hip/hip_runtime.h>

// Shapes (fixed by the problem):
#define F   256   // NUM_FEATURES
#define T   64    // SEQ (token axis)
#define NH  8     // heads
#define D   32    // head dim
#define NA  8     // agents
#define NBB 32    // batch per agent

// Q scale folded at projection time: 1/sqrt(F) * log2(e)  (exp2 softmax)
#define QSCALE (0.0625f * 1.44269504089f)

typedef unsigned short ushortT;
typedef unsigned int   uintT;

typedef short bf16x8 __attribute__((ext_vector_type(8)));
typedef float f32x4  __attribute__((ext_vector_type(4)));

__device__ __forceinline__ float bf2f(ushortT u) {
    union { uintT i; float f; } c; c.i = ((uintT)u) << 16; return c.f;
}
__device__ __forceinline__ ushortT f2bf(float f) {
    union { float f; uintT u; } c; c.f = f;
    uintT u = c.u;
    uintT r = u + 0x7fffu + ((u >> 16) & 1u);   // RNE
    return (ushortT)(r >> 16);
}

// Packed f32->bf16 conversion (1 VALU op for 2 values, RNE; T12 recipe).
__device__ __forceinline__ uintT cvt_pk_bf16(float lo, float hi) {
    uintT r;
    asm("v_cvt_pk_bf16_f32 %0, %1, %2" : "=v"(r) : "v"(lo), "v"(hi));
    return r;
}
__device__ __forceinline__ void packc1(const f32x4 v, uintT& u0, uintT& u1) {
    u0 = cvt_pk_bf16(v[0], v[1]);
    u1 = cvt_pk_bf16(v[2], v[3]);
}
__device__ __forceinline__ void packcs(const f32x4 v, float s, uintT& u0, uintT& u1) {
    u0 = cvt_pk_bf16(v[0] * s, v[1] * s);
    u1 = cvt_pk_bf16(v[2] * s, v[3] * s);
}

__device__ __forceinline__ float fexp2(float x) {
#if __has_builtin(__builtin_amdgcn_exp2f)
    return __builtin_amdgcn_exp2f(x);
#else
    float r; asm("v_exp_f32 %0, %1" : "=v"(r) : "v"(x)); return r;
#endif
}
__device__ __forceinline__ float frcp(float x) {
#if __has_builtin(__builtin_amdgcn_rcpf)
    return __builtin_amdgcn_rcpf(x);
#else
    float r; asm("v_rcp_f32 %0, %1" : "=v"(r) : "v"(x)); return r;
#endif
}

// Runtime dtype detection (verified: harness inputs are fp32).
__device__ __forceinline__ int detect_isbf16(const void* xraw) {
    const uintT* w = (const uintT*)xraw;
    int bad = 0;
    for (int k = 0; k < 128; ++k) {
        uintT v = w[k];
        uintT e0 = (v >> 7)  & 0xffu;
        uintT e1 = (v >> 23) & 0xffu;
        bad += (e0 > 131u) + (e1 > 131u);
    }
    return bad == 0 ? 1 : 0;
}

__device__ __forceinline__ ushortT cvt_elem(const void* p, size_t i, bool isbf) {
    return isbf ? ((const ushortT*)p)[i] : f2bf(((const float*)p)[i]);
}

// C-layout -> A/B-fragment transform via register shuffles (verified).
__device__ __forceinline__ bf16x8 build_frag(uintT u0a, uintT u1a, uintT u0b, uintT u1b,
                                             int sl0, int sl1, bool hi) {
    union { uintT u[4]; bf16x8 v; } r;
    uintT x0a = (uintT)__shfl((int)u0a, sl0), x0b = (uintT)__shfl((int)u0b, sl0);
    uintT x1a = (uintT)__shfl((int)u1a, sl0), x1b = (uintT)__shfl((int)u1b, sl0);
    uintT x2a = (uintT)__shfl((int)u0a, sl1), x2b = (uintT)__shfl((int)u0b, sl1);
    uintT x3a = (uintT)__shfl((int)u1a, sl1), x3b = (uintT)__shfl((int)u1b, sl1);
    r.u[0] = hi ? x0b : x0a;
    r.u[1] = hi ? x1b : x1a;
    r.u[2] = hi ? x2b : x2a;
    r.u[3] = hi ? x3b : x3a;
    return r.v;
}

// LDS tile: row t, 16B chunks XOR-swizzled by t -> b128 frag reads spread over
// all 8 bank-groups (2-way max = free per m136).  t is the LOCAL row (0..31).
__device__ __forceinline__ int xposU(int t, int f) {
    return t * 256 + ((((f >> 3) ^ (t & 31)) * 8) | (f & 7));
}
#define FRAGPOS(t_, ks_, quad_) \
    ((t_) * 256 + ((((4 * (ks_) + (quad_)) ^ ((t_) & 31)) * 8)))

// ===========================================================================
// ws layout (bytes):
//   0        Wt   [c'=1024][f=256] bf16   524288
//            (c'<256:Q, <512:K, <768:V, >=768: Wp[g][c])
//   524288   Kws  [nb][h][s][d] bf16     8388608
//   8912896  Vws  [nb][h][d][s] bf16     8388608  (transposed)
//   17301504 Qws  [nb][h][t][d] bf16     8388608  (scaled by QSCALE; needB)
// needA = 17301504 (R8 path), needB = 25690112 (Q-precompute path)
// ===========================================================================

// K0: weight prep. 262144 elems, grid 128 x 256, 8 elems/thread.
__global__ __launch_bounds__(256) void wprep_kernel(const void* __restrict__ Wq,
                                                    const void* __restrict__ Wk,
                                                    const void* __restrict__ Wv,
                                                    const void* __restrict__ Wp,
                                                    const void* __restrict__ x,
                                                    ushortT* __restrict__ Wt) {
    __shared__ int sflag;
    if (threadIdx.x == 0) sflag = detect_isbf16(x);
    __syncthreads();
    bool isbf = sflag != 0;

    int base = (blockIdx.x * 256 + threadIdx.x) * 8;   // < 262144
    int cp = base >> 8, f0 = base & 255;

    ushortT tmp[8];
    if (cp < 768) {   // QKV: transpose W*[h][f][d] -> Wt[c'][f]
        int qkv = cp >> 8, c = cp & 255, hh = c >> 5, d = c & 31;
        const void* W = (qkv == 0) ? Wq : (qkv == 1) ? Wk : Wv;
        #pragma unroll
        for (int jj = 0; jj < 8; ++jj)
            tmp[jj] = cvt_elem(W, (size_t)(hh * F + f0 + jj) * D + d, isbf);
    } else {          // Wp[g][c] straight copy (already row-major in c)
        int g = cp - 768;
        #pragma unroll
        for (int jj = 0; jj < 8; ++jj)
            tmp[jj] = cvt_elem(Wp, (size_t)g * F + f0 + jj, isbf);
    }
    *(uint4*)&Wt[base] = *(const uint4*)tmp;
}

// Stage full x[nb] tile -> xs[t64][f^swz] (32 KB).
template <int NT>
__device__ __forceinline__ void stage_xT(const void* x, int nb, ushortT* xs,
                                         bool isbf, int tid) {
    int t = tid & 63;
    int g0 = tid >> 6;
    const int GP = NT / 64;
    #pragma unroll
    for (int it = 0; it < 64 / GP; ++it) {
        int g = g0 + it * GP;
        float v0, v1, v2, v3;
        if (isbf) {
            const ushortT* xp = (const ushortT*)x + (size_t)nb * (F * T) + (size_t)g * 4 * T + t;
            v0 = bf2f(xp[0]); v1 = bf2f(xp[T]); v2 = bf2f(xp[2 * T]); v3 = bf2f(xp[3 * T]);
        } else {
            const float* xp = (const float*)x + (size_t)nb * (F * T) + (size_t)g * 4 * T + t;
            v0 = xp[0]; v1 = xp[T]; v2 = xp[2 * T]; v3 = xp[3 * T];
        }
        uintT lo  = cvt_pk_bf16(v0, v1);
        uintT hi2 = cvt_pk_bf16(v2, v3);
        *(uint2*)&xs[xposU(t & 31, g * 4) + (t >> 5) * 8192] = make_uint2(lo, hi2);
    }
}

// ---------------------------------------------------------------------------
// K1-B: Q/K/V projection GEMM (needB path).  grid = 256, 768 thr (12 waves).
// Waves 0-3: K rows (Wt 256..511) -> Kws; waves 4-7: V rows (512..767) ->
// Vws^T; waves 8-11: Q rows (0..255) -> Qws[nb][h][t][d], SCALED by QSCALE.
// R16: Q moved here from attn — reuses the already-staged x tile (attn's
// x-stage + Q-GEMM + pack/shuffle prologue was serial overhead in all 512
// attn blocks; qkv has idle capacity, never in rocprof top-5).
// Qws[t][d] reloads directly as the QK-MFMA B-operand fragment:
// lane(quad,l15) <- Q[t=l15][d=8q..8q+7] — bit-identical to the old
// packcs+build_frag values (same mfma inputs, same cvt_pk rounding).
// ---------------------------------------------------------------------------
__global__ __launch_bounds__(768) void qkvq_kernel(const void* __restrict__ x,
                                                   const ushortT* __restrict__ Wt,
                                                   ushortT* __restrict__ Kws,
                                                   ushortT* __restrict__ Vws,
                                                   ushortT* __restrict__ Qws) {
    int nb = blockIdx.x;
    __shared__ __align__(16) ushortT xs[T * F];   // 32 KB
    __shared__ int sflag;
    int tid = threadIdx.x;
    if (tid == 0) sflag = detect_isbf16(x);
    __syncthreads();
    bool isbf = sflag != 0;
    if (tid < 512) stage_xT<512>(x, nb, xs, isbf, tid);
    __syncthreads();

    int w = tid >> 6, lane = tid & 63, l15 = lane & 15, quad = lane >> 4;
    int cls = w >> 2;                  // 0:K (w0-3)  1:V (w4-7)  2:Q (w8-11)
    int rowbase = (cls == 2) ? 64 * (w - 8) : 256 + 64 * w;

    f32x4 acc[4][4];
    #pragma unroll
    for (int a = 0; a < 4; ++a)
        #pragma unroll
        for (int c = 0; c < 4; ++c) acc[a][c] = (f32x4){0.f, 0.f, 0.f, 0.f};

    #pragma unroll
    for (int ks = 0; ks < 8; ++ks) {
        bf16x8 Bfr[4];
        #pragma unroll
        for (int nt = 0; nt < 4; ++nt) {
            int t = 16 * nt + l15;
            Bfr[nt] = *(const bf16x8*)&xs[FRAGPOS(t & 31, ks, quad) + (t >> 5) * 8192];
        }
        #pragma unroll
        for (int mt = 0; mt < 4; ++mt) {
            bf16x8 Afr = *(const bf16x8*)(Wt +
                (size_t)(rowbase + 16 * mt + l15) * 256 + ks * 32 + quad * 8);
            #pragma unroll
            for (int nt = 0; nt < 4; ++nt)
                acc[mt][nt] = __builtin_amdgcn_mfma_f32_16x16x32_bf16(Afr, Bfr[nt],
                                                                      acc[mt][nt], 0, 0, 0);
        }
    }

    #pragma unroll
    for (int mt = 0; mt < 4; ++mt) {
        int rel = 64 * (w & 3) + 16 * mt + 4 * quad;   // 0..255 within class block
        int hh = rel >> 5, db = rel & 31;
        #pragma unroll
        for (int nt = 0; nt < 4; ++nt) {
            int t = 16 * nt + l15;
            f32x4 v = acc[mt][nt];
            if (cls == 0) {        // K: [nb][h][s=t][d]
                ushortT* dst = Kws + ((size_t)(nb * NH + hh) * T + t) * D + db;
                uintT lo  = cvt_pk_bf16(v[0], v[1]);
                uintT hi2 = cvt_pk_bf16(v[2], v[3]);
                *(uint2*)dst = make_uint2(lo, hi2);
            } else if (cls == 1) { // V transposed: [nb][h][d][s=t]
                uintT p0 = cvt_pk_bf16(v[0], v[1]);
                uintT p1 = cvt_pk_bf16(v[2], v[3]);
                size_t vb = (size_t)(nb * NH + hh) * D + db;
                Vws[(vb + 0) * T + t] = (ushortT)p0;
                Vws[(vb + 1) * T + t] = (ushortT)(p0 >> 16);
                Vws[(vb + 2) * T + t] = (ushortT)p1;
                Vws[(vb + 3) * T + t] = (ushortT)(p1 >> 16);
            } else {               // Q (scaled): [nb][h][t][d]
                ushortT* dst = Qws + ((size_t)(nb * NH + hh) * T + t) * D + db;
                uintT lo  = cvt_pk_bf16(v[0] * QSCALE, v[1] * QSCALE);
                uintT hi2 = cvt_pk_bf16(v[2] * QSCALE, v[3] * QSCALE);
                *(uint2*)dst = make_uint2(lo, hi2);
            }
        }
    }
}

// ---------------------------------------------------------------------------
// K2-B: attention + projection (needB path).  grid (b=32, j=8, tb=2),
// 512 thr, wave = head h.  Agent loop + epilogue = R8-verified body.
// R16: NO x-stage, NO Q-GEMM, NO Q pack/shuffle — qf loads straight from
// Qws (2 x 16B per wave).  Removes the serial prologue from all 512 blocks.
// ---------------------------------------------------------------------------
__global__ __launch_bounds__(512, 2) void attnq_kernel(const void* __restrict__ x,
                                                       const ushortT* __restrict__ Wt,
                                                       const ushortT* __restrict__ Kws,
                                                       const ushortT* __restrict__ Vws,
                                                       const ushortT* __restrict__ Qws,
                                                       const void* __restrict__ bp,
                                                       void* __restrict__ outp) {
    __shared__ __align__(16) ushortT xs[32 * F];   // 16 KB (Y buffer)
    __shared__ float bpf[F];
    __shared__ int sflag;

    int tid = threadIdx.x;
    int b = blockIdx.x, j = blockIdx.y, tb = blockIdx.z;
    int nbj = j * NBB + b;

    if (tid == 0) sflag = detect_isbf16(x);
    if (tid < 256)
        bpf[tid] = 0.f;   // placeholder; real fill below after sflag known
    __syncthreads();
    bool isbf = sflag != 0;
    if (tid < 256)
        bpf[tid] = isbf ? bf2f(((const ushortT*)bp)[tid]) : ((const float*)bp)[tid];

    int h = tid >> 6, lane = tid & 63, l15 = lane & 15, quad = lane >> 4;
    bool hi = quad >= 2;
    int sl0 = l15 + 32 * (quad & 1), sl1 = sl0 + 16;

    // ---- Q fragments: direct load (B-operand layout), scale pre-folded
    const ushortT* Qb = Qws + ((size_t)nbj * NH + h) * T * D;
    bf16x8 qf[2];
    qf[0] = *(const bf16x8*)(Qb + (size_t)(tb * 32 + l15) * D + quad * 8);
    qf[1] = *(const bf16x8*)(Qb + (size_t)(tb * 32 + 16 + l15) * D + quad * 8);

    f32x4 oacc[2][2];
    #pragma unroll
    for (int mt = 0; mt < 2; ++mt)
        #pragma unroll
        for (int tt = 0; tt < 2; ++tt) oacc[mt][tt] = (f32x4){0.f, 0.f, 0.f, 0.f};

    // ---- key-agent loop (R8-verified body)
    for (int i = 0; i < NA; ++i) {
        int nbi = i * NBB + b;
        const ushortT* Kb = Kws + (size_t)(nbi * NH + h) * T * D;
        const ushortT* Vb = Vws + (size_t)(nbi * NH + h) * D * T;

        float psum[2] = {0.f, 0.f};
        f32x4 pv[2][2];
        #pragma unroll
        for (int mt = 0; mt < 2; ++mt)
            #pragma unroll
            for (int tt = 0; tt < 2; ++tt) pv[mt][tt] = (f32x4){0.f, 0.f, 0.f, 0.f};

        #pragma unroll
        for (int kx = 0; kx < 2; ++kx) {
            bf16x8 kfr[2];
            kfr[0] = *(const bf16x8*)(Kb + (16 * (2 * kx + 0) + l15) * D + quad * 8);
            kfr[1] = *(const bf16x8*)(Kb + (16 * (2 * kx + 1) + l15) * D + quad * 8);
            bf16x8 vf0 = *(const bf16x8*)(Vb + l15 * T + kx * 32 + quad * 8);
            bf16x8 vf1 = *(const bf16x8*)(Vb + (16 + l15) * T + kx * 32 + quad * 8);

            uintT pu0[2][2], pu1[2][2];   // [sp][tt]
            #pragma unroll
            for (int sp = 0; sp < 2; ++sp) {
                #pragma unroll
                for (int tt = 0; tt < 2; ++tt) {
                    f32x4 s4 = __builtin_amdgcn_mfma_f32_16x16x32_bf16(
                        kfr[sp], qf[tt], (f32x4){0.f, 0.f, 0.f, 0.f}, 0, 0, 0);
                    float e0 = fexp2(s4[0]);
                    float e1 = fexp2(s4[1]);
                    float e2 = fexp2(s4[2]);
                    float e3 = fexp2(s4[3]);
                    psum[tt] += (e0 + e1) + (e2 + e3);
                    pu0[sp][tt] = cvt_pk_bf16(e0, e1);
                    pu1[sp][tt] = cvt_pk_bf16(e2, e3);
                }
            }
            #pragma unroll
            for (int tt = 0; tt < 2; ++tt) {
                bf16x8 pf = build_frag(pu0[0][tt], pu1[0][tt], pu0[1][tt], pu1[1][tt],
                                       sl0, sl1, hi);
                pv[0][tt] = __builtin_amdgcn_mfma_f32_16x16x32_bf16(
                    vf0, pf, pv[0][tt], 0, 0, 0);
                pv[1][tt] = __builtin_amdgcn_mfma_f32_16x16x32_bf16(
                    vf1, pf, pv[1][tt], 0, 0, 0);
            }
        }

        #pragma unroll
        for (int tt = 0; tt < 2; ++tt) {
            float s = psum[tt];
            s += __shfl_xor(s, 16);
            s += __shfl_xor(s, 32);
            float inv = frcp(s);
            #pragma unroll
            for (int mt = 0; mt < 2; ++mt)
                #pragma unroll
                for (int r = 0; r < 4; ++r)
                    oacc[mt][tt][r] = fmaf(inv, pv[mt][tt][r], oacc[mt][tt][r]);
        }
    }

    // ---- epilogue: Y[t32][c] -> xs (swizzled; waves write disjoint columns)
    #pragma unroll
    for (int mt = 0; mt < 2; ++mt)
        #pragma unroll
        for (int tt = 0; tt < 2; ++tt) {
            int t = 16 * tt + l15;
            int cb = 32 * h + 16 * mt + 4 * quad;
            uintT u0, u1;
            packc1(oacc[mt][tt], u0, u1);
            *(uint2*)&xs[xposU(t, cb)] = make_uint2(u0, u1);
        }
    __syncthreads();

    // OUT[g][t32] = Wp[g][c] . Y[t][c] + bp[g];  wave h -> g-tiles 2h, 2h+1
    f32x4 cacc[2][2];
    #pragma unroll
    for (int a = 0; a < 2; ++a)
        #pragma unroll
        for (int c = 0; c < 2; ++c) cacc[a][c] = (f32x4){0.f, 0.f, 0.f, 0.f};

    #pragma unroll
    for (int ks = 0; ks < 8; ++ks) {
        bf16x8 yb[2];
        #pragma unroll
        for (int nt = 0; nt < 2; ++nt)
            yb[nt] = *(const bf16x8*)&xs[FRAGPOS(16 * nt + l15, ks, quad)];
        #pragma unroll
        for (int m2 = 0; m2 < 2; ++m2) {
            int g = 16 * (2 * h + m2) + l15;
            bf16x8 wf = *(const bf16x8*)(Wt + (size_t)(768 + g) * 256 + ks * 32 + quad * 8);
            #pragma unroll
            for (int nt = 0; nt < 2; ++nt)
                cacc[m2][nt] = __builtin_amdgcn_mfma_f32_16x16x32_bf16(
                    wf, yb[nt], cacc[m2][nt], 0, 0, 0);
        }
    }

    #pragma unroll
    for (int m2 = 0; m2 < 2; ++m2)
        #pragma unroll
        for (int nt = 0; nt < 2; ++nt) {
            int t = tb * 32 + 16 * nt + l15;
            #pragma unroll
            for (int r = 0; r < 4; ++r) {
                int g = 16 * (2 * h + m2) + 4 * quad + r;
                float val = cacc[m2][nt][r] + bpf[g];
                if (isbf)
                    ((ushortT*)outp)[(size_t)nbj * F * T + g * T + t] = f2bf(val);
                else
                    ((float*)outp)[(size_t)nbj * F * T + g * T + t] = val;
            }
        }
}

// ---------------------------------------------------------------------------
// K1-A: K/V projection GEMM (needA fallback = R8-verified, 146.7 µs total).
// ---------------------------------------------------------------------------
__global__ __launch_bounds__(512) void qkv_kernel(const void* __restrict__ x,
                                                  const ushortT* __restrict__ Wt,
                                                  ushortT* __restrict__ Kws,
                                                  ushortT* __restrict__ Vws) {
    int nb = blockIdx.x;
    __shared__ __align__(16) ushortT xs[T * F];   // 32 KB
    __shared__ int sflag;
    int tid = threadIdx.x;
    if (tid == 0) sflag = detect_isbf16(x);
    __syncthreads();
    bool isbf = sflag != 0;
    stage_xT<512>(x, nb, xs, isbf, tid);
    __syncthreads();

    int w = tid >> 6, lane = tid & 63, l15 = lane & 15, quad = lane >> 4;
    int half = w >> 2;                 // 0 = K (waves 0-3), 1 = V (waves 4-7)
    int rowbase = 256 + 64 * w;        // spans K rows then V rows

    f32x4 acc[4][4];
    #pragma unroll
    for (int a = 0; a < 4; ++a)
        #pragma unroll
        for (int c = 0; c < 4; ++c) acc[a][c] = (f32x4){0.f, 0.f, 0.f, 0.f};

    #pragma unroll
    for (int ks = 0; ks < 8; ++ks) {
        bf16x8 Bfr[4];
        #pragma unroll
        for (int nt = 0; nt < 4; ++nt) {
            int t = 16 * nt + l15;
            Bfr[nt] = *(const bf16x8*)&xs[FRAGPOS(t & 31, ks, quad) + (t >> 5) * 8192];
        }
        #pragma unroll
        for (int mt = 0; mt < 4; ++mt) {
            bf16x8 Afr = *(const bf16x8*)(Wt +
                (size_t)(rowbase + 16 * mt + l15) * 256 + ks * 32 + quad * 8);
            #pragma unroll
            for (int nt = 0; nt < 4; ++nt)
                acc[mt][nt] = __builtin_amdgcn_mfma_f32_16x16x32_bf16(Afr, Bfr[nt],
                                                                      acc[mt][nt], 0, 0, 0);
        }
    }

    #pragma unroll
    for (int mt = 0; mt < 4; ++mt) {
        int rel = 64 * (w & 3) + 16 * mt + 4 * quad;   // 0..255 within K or V block
        int hh = rel >> 5, db = rel & 31;
        #pragma unroll
        for (int nt = 0; nt < 4; ++nt) {
            int t = 16 * nt + l15;
            f32x4 v = acc[mt][nt];
            if (half == 0) {   // K: [nb][h][s=t][d]
                ushortT* dst = Kws + ((size_t)(nb * NH + hh) * T + t) * D + db;
                uintT lo  = cvt_pk_bf16(v[0], v[1]);
                uintT hi2 = cvt_pk_bf16(v[2], v[3]);
                *(uint2*)dst = make_uint2(lo, hi2);
            } else {           // V transposed: [nb][h][d][s=t]
                uintT p0 = cvt_pk_bf16(v[0], v[1]);
                uintT p1 = cvt_pk_bf16(v[2], v[3]);
                size_t vb = (size_t)(nb * NH + hh) * D + db;
                Vws[(vb + 0) * T + t] = (ushortT)p0;
                Vws[(vb + 1) * T + t] = (ushortT)(p0 >> 16);
                Vws[(vb + 2) * T + t] = (ushortT)p1;
                Vws[(vb + 3) * T + t] = (ushortT)(p1 >> 16);
            }
        }
    }
}

// ---------------------------------------------------------------------------
// K2-A: attention (needA fallback = R8-verified body with in-kernel Q-GEMM).
// ---------------------------------------------------------------------------
__global__ __launch_bounds__(512, 2) void attn_kernel(const void* __restrict__ x,
                                                      const ushortT* __restrict__ Wt,
                                                      const ushortT* __restrict__ Kws,
                                                      const ushortT* __restrict__ Vws,
                                                      const void* __restrict__ bp,
                                                      void* __restrict__ outp) {
    __shared__ __align__(16) ushortT xs[32 * F];   // 16 KB
    __shared__ float bpf[F];
    __shared__ int sflag;

    int tid = threadIdx.x;
    int b = blockIdx.x, j = blockIdx.y, tb = blockIdx.z;
    int nbj = j * NBB + b;

    if (tid == 0) sflag = detect_isbf16(x);
    __syncthreads();
    bool isbf = sflag != 0;

    {
        int t = tid & 31, fg = tid >> 5;
        int ta = tb * 32 + t;
        #pragma unroll
        for (int it = 0; it < 4; ++it) {
            int f0 = (fg + 16 * it) * 4;
            float v0, v1, v2, v3;
            if (isbf) {
                const ushortT* xp = (const ushortT*)x + (size_t)nbj * (F * T) +
                                    (size_t)f0 * T + ta;
                v0 = bf2f(xp[0]); v1 = bf2f(xp[T]); v2 = bf2f(xp[2 * T]); v3 = bf2f(xp[3 * T]);
            } else {
                const float* xp = (const float*)x + (size_t)nbj * (F * T) +
                                  (size_t)f0 * T + ta;
                v0 = xp[0]; v1 = xp[T]; v2 = xp[2 * T]; v3 = xp[3 * T];
            }
            uintT lo  = cvt_pk_bf16(v0, v1);
            uintT hi2 = cvt_pk_bf16(v2, v3);
            *(uint2*)&xs[xposU(t, f0)] = make_uint2(lo, hi2);
        }
    }
    if (tid < 256)
        bpf[tid] = isbf ? bf2f(((const ushortT*)bp)[tid]) : ((const float*)bp)[tid];
    __syncthreads();

    int h = tid >> 6, lane = tid & 63, l15 = lane & 15, quad = lane >> 4;
    bool hi = quad >= 2;
    int sl0 = l15 + 32 * (quad & 1), sl1 = sl0 + 16;

    const float QS = QSCALE;
    bf16x8 qf[2];
    {
        f32x4 qacc[2][2];
        #pragma unroll
        for (int mt = 0; mt < 2; ++mt)
            #pragma unroll
            for (int nt = 0; nt < 2; ++nt) qacc[mt][nt] = (f32x4){0.f, 0.f, 0.f, 0.f};
        #pragma unroll
        for (int ks = 0; ks < 8; ++ks) {
            bf16x8 xf[2];
            #pragma unroll
            for (int nt = 0; nt < 2; ++nt)
                xf[nt] = *(const bf16x8*)&xs[FRAGPOS(16 * nt + l15, ks, quad)];
            #pragma unroll
            for (int mt = 0; mt < 2; ++mt) {
                bf16x8 Aw = *(const bf16x8*)(Wt +
                    (size_t)(32 * h + 16 * mt + l15) * 256 + ks * 32 + quad * 8);
                #pragma unroll
                for (int nt = 0; nt < 2; ++nt)
                    qacc[mt][nt] = __builtin_amdgcn_mfma_f32_16x16x32_bf16(
                        Aw, xf[nt], qacc[mt][nt], 0, 0, 0);
            }
        }
        #pragma unroll
        for (int tt = 0; tt < 2; ++tt) {
            uintT a0, a1, b0, b1;
            packcs(qacc[0][tt], QS, a0, a1);
            packcs(qacc[1][tt], QS, b0, b1);
            qf[tt] = build_frag(a0, a1, b0, b1, sl0, sl1, hi);
        }
    }

    f32x4 oacc[2][2];
    #pragma unroll
    for (int mt = 0; mt < 2; ++mt)
        #pragma unroll
        for (int tt = 0; tt < 2; ++tt) oacc[mt][tt] = (f32x4){0.f, 0.f, 0.f, 0.f};

    for (int i = 0; i < NA; ++i) {
        int nbi = i * NBB + b;
        const ushortT* Kb = Kws + (size_t)(nbi * NH + h) * T * D;
        const ushortT* Vb = Vws + (size_t)(nbi * NH + h) * D * T;

        float psum[2] = {0.f, 0.f};
        f32x4 pv[2][2];
        #pragma unroll
        for (int mt = 0; mt < 2; ++mt)
            #pragma unroll
            for (int tt = 0; tt < 2; ++tt) pv[mt][tt] = (f32x4){0.f, 0.f, 0.f, 0.f};

        #pragma unroll
        for (int kx = 0; kx < 2; ++kx) {
            bf16x8 kfr[2];
            kfr[0] = *(const bf16x8*)(Kb + (16 * (2 * kx + 0) + l15) * D + quad * 8);
            kfr[1] = *(const bf16x8*)(Kb + (16 * (2 * kx + 1) + l15) * D + quad * 8);
            bf16x8 vf0 = *(const bf16x8*)(Vb + l15 * T + kx * 32 + quad * 8);
            bf16x8 vf1 = *(const bf16x8*)(Vb + (16 + l15) * T + kx * 32 + quad * 8);

            uintT pu0[2][2], pu1[2][2];   // [sp][tt]
            #pragma unroll
            for (int sp = 0; sp < 2; ++sp) {
                #pragma unroll
                for (int tt = 0; tt < 2; ++tt) {
                    f32x4 s4 = __builtin_amdgcn_mfma_f32_16x16x32_bf16(
                        kfr[sp], qf[tt], (f32x4){0.f, 0.f, 0.f, 0.f}, 0, 0, 0);
                    float e0 = fexp2(s4[0]);
                    float e1 = fexp2(s4[1]);
                    float e2 = fexp2(s4[2]);
                    float e3 = fexp2(s4[3]);
                    psum[tt] += (e0 + e1) + (e2 + e3);
                    pu0[sp][tt] = cvt_pk_bf16(e0, e1);
                    pu1[sp][tt] = cvt_pk_bf16(e2, e3);
                }
            }
            #pragma unroll
            for (int tt = 0; tt < 2; ++tt) {
                bf16x8 pf = build_frag(pu0[0][tt], pu1[0][tt], pu0[1][tt], pu1[1][tt],
                                       sl0, sl1, hi);
                pv[0][tt] = __builtin_amdgcn_mfma_f32_16x16x32_bf16(
                    vf0, pf, pv[0][tt], 0, 0, 0);
                pv[1][tt] = __builtin_amdgcn_mfma_f32_16x16x32_bf16(
                    vf1, pf, pv[1][tt], 0, 0, 0);
            }
        }

        #pragma unroll
        for (int tt = 0; tt < 2; ++tt) {
            float s = psum[tt];
            s += __shfl_xor(s, 16);
            s += __shfl_xor(s, 32);
            float inv = frcp(s);
            #pragma unroll
            for (int mt = 0; mt < 2; ++mt)
                #pragma unroll
                for (int r = 0; r < 4; ++r)
                    oacc[mt][tt][r] = fmaf(inv, pv[mt][tt][r], oacc[mt][tt][r]);
        }
    }

    __syncthreads();
    #pragma unroll
    for (int mt = 0; mt < 2; ++mt)
        #pragma unroll
        for (int tt = 0; tt < 2; ++tt) {
            int t = 16 * tt + l15;
            int cb = 32 * h + 16 * mt + 4 * quad;
            uintT u0, u1;
            packc1(oacc[mt][tt], u0, u1);
            *(uint2*)&xs[xposU(t, cb)] = make_uint2(u0, u1);
        }
    __syncthreads();

    f32x4 cacc[2][2];
    #pragma unroll
    for (int a = 0; a < 2; ++a)
        #pragma unroll
        for (int c = 0; c < 2; ++c) cacc[a][c] = (f32x4){0.f, 0.f, 0.f, 0.f};

    #pragma unroll
    for (int ks = 0; ks < 8; ++ks) {
        bf16x8 yb[2];
        #pragma unroll
        for (int nt = 0; nt < 2; ++nt)
            yb[nt] = *(const bf16x8*)&xs[FRAGPOS(16 * nt + l15, ks, quad)];
        #pragma unroll
        for (int m2 = 0; m2 < 2; ++m2) {
            int g = 16 * (2 * h + m2) + l15;
            bf16x8 wf = *(const bf16x8*)(Wt + (size_t)(768 + g) * 256 + ks * 32 + quad * 8);
            #pragma unroll
            for (int nt = 0; nt < 2; ++nt)
                cacc[m2][nt] = __builtin_amdgcn_mfma_f32_16x16x32_bf16(
                    wf, yb[nt], cacc[m2][nt], 0, 0, 0);
        }
    }

    #pragma unroll
    for (int m2 = 0; m2 < 2; ++m2)
        #pragma unroll
        for (int nt = 0; nt < 2; ++nt) {
            int t = tb * 32 + 16 * nt + l15;
            #pragma unroll
            for (int r = 0; r < 4; ++r) {
                int g = 16 * (2 * h + m2) + 4 * quad + r;
                float val = cacc[m2][nt][r] + bpf[g];
                if (isbf)
                    ((ushortT*)outp)[(size_t)nbj * F * T + g * T + t] = f2bf(val);
                else
                    ((float*)outp)[(size_t)nbj * F * T + g * T + t] = val;
            }
        }
}

// ===========================================================================
// PATH B: zero-workspace scalar fallback (verified, dtype-flexible).
// ===========================================================================
__device__ __forceinline__ float tof(ushortT u) { return bf2f(u); }
__device__ __forceinline__ float tof(float f)   { return f; }

__device__ __forceinline__ void stage_x(const void* x, size_t nb, ushortT* sX,
                                        bool isbf, int tid) {
    if (isbf) {
        const int4* xg = (const int4*)((const ushortT*)x + nb * (F * T));
        int4* xl = (int4*)sX;
        for (int kk = tid; kk < F * T / 8; kk += 512) xl[kk] = xg[kk];
    } else {
        const float4* xg = (const float4*)((const float*)x + nb * (F * T));
        for (int kk = tid; kk < F * T / 4; kk += 512) {
            float4 v = xg[kk];
            int o = kk * 4;
            sX[o + 0] = f2bf(v.x); sX[o + 1] = f2bf(v.y);
            sX[o + 2] = f2bf(v.z); sX[o + 3] = f2bf(v.w);
        }
    }
}

template <typename WT>
__device__ __forceinline__ void q_proj(const WT* __restrict__ W, const ushortT* sX,
                                       ushortT* dst, int c, int t0) {
    float acc[32];
    #pragma unroll
    for (int m = 0; m < 32; ++m) acc[m] = 0.f;
    for (int f = 0; f < F; ++f) {
        float w = tof(W[f * D]);
        const ushortT* xr = &sX[f * T + t0];
        #pragma unroll
        for (int m = 0; m < 32; ++m) acc[m] = fmaf(bf2f(xr[m]), w, acc[m]);
    }
    #pragma unroll
    for (int m = 0; m < 32; ++m) dst[(t0 + m) * F + c] = f2bf(acc[m]);
}

template <typename WT>
__device__ __forceinline__ void kv_proj(const WT* __restrict__ WK, const WT* __restrict__ WV,
                                        const ushortT* sX, ushortT* sK, ushortT* sV,
                                        int c, int t0) {
    float ak[32], av[32];
    #pragma unroll
    for (int m = 0; m < 32; ++m) { ak[m] = 0.f; av[m] = 0.f; }
    for (int f = 0; f < F; ++f) {
        float wk = tof(WK[f * D]);
        float wv = tof(WV[f * D]);
        const ushortT* xr = &sX[f * T + t0];
        #pragma unroll
        for (int m = 0; m < 32; ++m) {
            float xv = bf2f(xr[m]);
            ak[m] = fmaf(xv, wk, ak[m]);
            av[m] = fmaf(xv, wv, av[m]);
        }
    }
    #pragma unroll
    for (int m = 0; m < 32; ++m) {
        sK[(t0 + m) * F + c] = f2bf(ak[m]);
        sV[(t0 + m) * F + c] = f2bf(av[m]);
    }
}

__global__ __launch_bounds__(512) void fused_kernel(const void* __restrict__ x,
                                                    const void* __restrict__ Wq,
                                                    const void* __restrict__ Wk,
                                                    const void* __restrict__ Wv,
                                                    const void* __restrict__ Wp,
                                                    const void* __restrict__ bp,
                                                    void* __restrict__ outp) {
    __shared__ __align__(16) char smem[98304];
    __shared__ int sflag;
    ushortT* sX = (ushortT*)smem;
    ushortT* sK = (ushortT*)(smem + 32768);
    ushortT* sV = (ushortT*)(smem + 65536);
    float*   sO = (float*)smem;

    int tid = threadIdx.x;
    int b = blockIdx.x, j = blockIdx.y;
    size_t nbj = (size_t)j * NBB + b;

    if (tid == 0) sflag = detect_isbf16(x);
    __syncthreads();
    bool isbf = sflag != 0;

    stage_x(x, nbj, sX, isbf, tid);
    __syncthreads();

    int c = tid & 255, t0 = (tid >> 8) * 32;
    int hc = c >> 5, dc = c & 31;
    if (isbf) q_proj((const ushortT*)Wq + (size_t)hc * F * D + dc, sX, sK, c, t0);
    else      q_proj((const float*)Wq   + (size_t)hc * F * D + dc, sX, sK, c, t0);
    __syncthreads();

    int h = tid >> 6, t = tid & 63;
    float q[32], o[32];
    #pragma unroll
    for (int dd = 0; dd < 32; ++dd) { q[dd] = bf2f(sK[t * F + h * D + dd]); o[dd] = 0.f; }

    for (int i = 0; i < NA; ++i) {
        __syncthreads();
        stage_x(x, (size_t)(i * NBB + b), sX, isbf, tid);
        __syncthreads();
        if (isbf) kv_proj((const ushortT*)Wk + (size_t)hc * F * D + dc,
                          (const ushortT*)Wv + (size_t)hc * F * D + dc, sX, sK, sV, c, t0);
        else      kv_proj((const float*)Wk   + (size_t)hc * F * D + dc,
                          (const float*)Wv   + (size_t)hc * F * D + dc, sX, sK, sV, c, t0);
        __syncthreads();
        float l = 0.f;
        float oi[32];
        #pragma unroll
        for (int dd = 0; dd < 32; ++dd) oi[dd] = 0.f;
        for (int s = 0; s < T; ++s) {
            const ushortT* kr = &sK[s * F + h * D];
            float dot = 0.f;
            #pragma unroll
            for (int dd = 0; dd < 32; ++dd) dot = fmaf(q[dd], bf2f(kr[dd]), dot);
            float e = __expf(dot * 0.0625f);
            l += e;
            const ushortT* vr = &sV[s * F + h * D];
            #pragma unroll
            for (int dd = 0; dd < 32; ++dd) oi[dd] = fmaf(e, bf2f(vr[dd]), oi[dd]);
        }
        float inv = 1.0f / l;
        #pragma unroll
        for (int dd = 0; dd < 32; ++dd) o[dd] = fmaf(inv, oi[dd], o[dd]);
    }
    __syncthreads();

    #pragma unroll
    for (int dd = 0; dd < 32; ++dd) sO[(h * D + dd) * T + t] = o[dd];
    __syncthreads();

    {
        int g = tid >> 1, te0 = (tid & 1) * 32;
        float acc[32];
        #pragma unroll
        for (int m = 0; m < 32; ++m) acc[m] = 0.f;
        if (isbf) {
            const ushortT* Wrow = (const ushortT*)Wp + (size_t)g * F;
            for (int cc = 0; cc < F; ++cc) {
                float w = bf2f(Wrow[cc]);
                const float* yr = &sO[cc * T + te0];
                #pragma unroll
                for (int m = 0; m < 32; ++m) acc[m] = fmaf(yr[m], w, acc[m]);
            }
        } else {
            const float* Wrow = (const float*)Wp + (size_t)g * F;
            for (int cc = 0; cc < F; ++cc) {
                float w = Wrow[cc];
                const float* yr = &sO[cc * T + te0];
                #pragma unroll
                for (int m = 0; m < 32; ++m) acc[m] = fmaf(yr[m], w, acc[m]);
            }
        }
        float bias = isbf ? bf2f(((const ushortT*)bp)[g]) : ((const float*)bp)[g];
        if (isbf) {
            ushortT* ob = (ushortT*)outp + nbj * F * T + g * T + te0;
            #pragma unroll
            for (int m = 0; m < 32; ++m) ob[m] = f2bf(acc[m] + bias);
        } else {
            float* ob = (float*)outp + nbj * F * T + g * T + te0;
            #pragma unroll
            for (int m = 0; m < 32; ++m) ob[m] = acc[m] + bias;
        }
    }
}

// ---------------------------------------------------------------------------
extern "C" void kernel_launch(void* const* d_in, const int* in_sizes, int n_in,
                              void* d_out, int out_size, void* d_ws, size_t ws_size,
                              hipStream_t stream) {
    const void* x  = d_in[0];
    const void* Wq = d_in[1];
    const void* Wk = d_in[2];
    const void* Wv = d_in[3];
    const void* Wp = d_in[4];
    const void* bp = d_in[5];

    const size_t needA = 17301504;              // Wt + Kws + Vws
    const size_t needB = needA + 8388608;       // + Qws

    if (ws_size >= needB) {
        char* ws = (char*)d_ws;
        ushortT* Wt  = (ushortT*)(ws + 0);
        ushortT* Kws = (ushortT*)(ws + 524288);
        ushortT* Vws = (ushortT*)(ws + 8912896);
        ushortT* Qws = (ushortT*)(ws + 17301504);

        wprep_kernel<<<dim3(128),      dim3(256), 0, stream>>>(Wq, Wk, Wv, Wp, x, Wt);
        qkvq_kernel <<<dim3(256),      dim3(768), 0, stream>>>(x, Wt, Kws, Vws, Qws);
        attnq_kernel<<<dim3(32, 8, 2), dim3(512), 0, stream>>>(x, Wt, Kws, Vws, Qws,
                                                               bp, d_out);
    } else if (ws_size >= needA) {
        char* ws = (char*)d_ws;
        ushortT* Wt  = (ushortT*)(ws + 0);
        ushortT* Kws = (ushortT*)(ws + 524288);
        ushortT* Vws = (ushortT*)(ws + 8912896);

        wprep_kernel<<<dim3(128),      dim3(256), 0, stream>>>(Wq, Wk, Wv, Wp, x, Wt);
        qkv_kernel  <<<dim3(256),      dim3(512), 0, stream>>>(x, Wt, Kws, Vws);
        attn_kernel <<<dim3(32, 8, 2), dim3(512), 0, stream>>>(x, Wt, Kws, Vws, bp, d_out);
    } else {
        fused_kernel<<<dim3(32, 8), dim3(512), 0, stream>>>(x, Wq, Wk, Wv, Wp, bp, d_out);
    }
}